// Round 3
// baseline (86.630 us; speedup 1.0000x reference)
//
#include <hip/hip_runtime.h>

#define BB 128
#define NN 16384
#define CC 8
#define WW 10
#define DD 3
#define LL 16375     // N - W + 1
#define LP 16392     // zero-padded weight length (covers l up to N-1)
#define SEG 8
#define CHLEN 32     // n's per (thread, batch)
#define BP 2         // batches per k_fir block

typedef float f2_t __attribute__((ext_vector_type(2)));

// ---------------------------------------------------------------------------
// K0: build w2t[l][c] = (wr[c,l], wi[c,l]) interleaved, zero-padded l in [LL,LP)
// ---------------------------------------------------------------------------
__global__ __launch_bounds__(256) void k_interleave(const float* __restrict__ wr,
                                                    const float* __restrict__ wi,
                                                    float* __restrict__ w2) {
  int idx = blockIdx.x * 256 + threadIdx.x;   // idx = l*8 + c
  if (idx >= LP * CC) return;
  int l = idx >> 3;
  int c = idx & 7;
  float a = 0.f, b = 0.f;
  if (l < LL) { a = wr[c * LL + l]; b = wi[c * LL + l]; }
  w2[2 * idx]     = a;
  w2[2 * idx + 1] = b;
}

// ---------------------------------------------------------------------------
// K1: main FIR. Grid = (B/BP)*SEG blocks x 512 threads.
// Block handles batches (b0, b0+1) over one seg of 2048 n's. Thread
// (c = tid&7, chunk = tid>>3) does 32 consecutive n's for BOTH batches with a
// shared 16-slot sliding register window of weights (1 w-load amortized over
// 2 batches). x loads are non-temporal (read-once stream) so w2 stays in L2.
// Epilogue: shfl_xor over the 3 in-wave chunk bits, then small LDS reduce.
// ---------------------------------------------------------------------------
__global__ __launch_bounds__(512, 4) void k_fir(const float* __restrict__ x,
                                                const float* __restrict__ w2,
                                                float* __restrict__ fpart) {
  int bp  = blockIdx.x >> 3;
  int seg = blockIdx.x & 7;
  int b0  = bp * BP;
  int tid = threadIdx.x;
  int c     = tid & 7;
  int chunk = tid >> 3;                        // 0..63
  int n0 = seg * (NN / SEG) + chunk * CHLEN;   // multiple of 16

  const f2_t* __restrict__ xpA = ((const f2_t*)x) + (size_t)(b0)     * NN * CC + c;
  const f2_t* __restrict__ xpB = ((const f2_t*)x) + (size_t)(b0 + 1) * NN * CC + c;
  const f2_t* __restrict__ wpt = ((const f2_t*)w2) + c;

  f2_t accA[WW], accB[WW];
#pragma unroll
  for (int w = 0; w < WW; ++w) { accA[w] = (f2_t)0.f; accB[w] = (f2_t)0.f; }

  f2_t ww[16];
#pragma unroll
  for (int s = 0; s < 16; ++s) ww[s] = (f2_t)0.f;
  // preload slots for l = n0-9 .. n0-1 (slot = l & 15); l<0 stays zero
#pragma unroll
  for (int j = 1; j <= 9; ++j) {
    int l = n0 - j;
    if (l >= 0) ww[(16 - j) & 15] = wpt[(size_t)l * CC];
  }

  for (int g = 0; g < CHLEN / 16; ++g) {
    int nb = n0 + g * 16;
#pragma unroll
    for (int u = 0; u < 16; ++u) {
      int n = nb + u;
      ww[u] = wpt[(size_t)n * CC];     // slot n&15 == u; padded rows make this safe
      f2_t xa = __builtin_nontemporal_load(&xpA[(size_t)n * CC]);
      f2_t xb = __builtin_nontemporal_load(&xpB[(size_t)n * CC]);
#pragma unroll
      for (int w = 0; w < WW; ++w) {
        f2_t wt = ww[(u - w + 16) & 15];
        accA[w][0] += xa[0] * wt[0];
        accA[w][1] += xa[1] * wt[1];
        accB[w][0] += xb[0] * wt[0];
        accB[w][1] += xb[1] * wt[1];
      }
    }
  }

  // reduce over the 8 in-wave chunks (lane bits 3..5)
#pragma unroll
  for (int m = 8; m < 64; m <<= 1) {
#pragma unroll
    for (int w = 0; w < WW; ++w) {
      accA[w][0] += __shfl_xor(accA[w][0], m);
      accA[w][1] += __shfl_xor(accA[w][1], m);
      accB[w][0] += __shfl_xor(accB[w][0], m);
      accB[w][1] += __shfl_xor(accB[w][1], m);
    }
  }

  // LDS: [wave][bi][w][c][ri] = 8*2*10*8*2 floats = 10 KB
  __shared__ float red[8 * 320];
  int wave = tid >> 6;
  int lane = tid & 63;
  if (lane < 8) {                // lane == c
#pragma unroll
    for (int w = 0; w < WW; ++w) {
      red[wave * 320 +       w * 16 + lane * 2 + 0] = accA[w][0];
      red[wave * 320 +       w * 16 + lane * 2 + 1] = accA[w][1];
      red[wave * 320 + 160 + w * 16 + lane * 2 + 0] = accB[w][0];
      red[wave * 320 + 160 + w * 16 + lane * 2 + 1] = accB[w][1];
    }
  }
  __syncthreads();
  if (tid < 320) {               // tid = bi*160 + r,  r = w*16 + c*2 + ri
    float s = 0.f;
#pragma unroll
    for (int wv = 0; wv < 8; ++wv) s += red[wv * 320 + tid];
    int bi = tid >> 7 >> 1;      // tid/160 == 0 or 1 (tid<160 -> 0)
    bi = (tid >= 160) ? 1 : 0;
    int r = tid - bi * 160;
    fpart[((size_t)(b0 + bi) * SEG + seg) * 160 + r] = s;
  }
}

// ---------------------------------------------------------------------------
// K2: seg-reduce + nonlin + projection + BatchNorm, fused. 1 block x 1024 thr.
// Two phases of 64 batches staged in LDS (42 KB). Thread (b2=tid>>4,
// c=(tid>>1)&7, p=tid&1) computes o for (b2, c, p) and (b2+64, c, p).
// ---------------------------------------------------------------------------
__global__ __launch_bounds__(1024) void k_final(const float* __restrict__ fpart,
                                                const float* __restrict__ wc,
                                                const float* __restrict__ wor,
                                                const float* __restrict__ woi,
                                                const float* __restrict__ gamma,
                                                const float* __restrict__ beta,
                                                float* __restrict__ out) {
  __shared__ float sred[64][164];
  __shared__ float swc[672];
  __shared__ float swout[160];
  __shared__ float ps[16][8], qs[16][8];
  __shared__ float mv[8], iv[8], bv[8];

  int tid = threadIdx.x;
  if (tid < 672) swc[tid] = wc[tid];
  if (tid >= 768 && tid < 848) swout[tid - 768] = wor[tid - 768];
  if (tid >= 848 && tid < 928) swout[tid - 768] = woi[tid - 848];

  int b2 = tid >> 4;
  int c  = (tid >> 1) & 7;
  int p  = tid & 1;

  const float4* fp4 = (const float4*)fpart;

  // ---- stage phase A (b = 0..63) ----
  for (int t = tid; t < 64 * 40; t += 1024) {
    int bl = t / 40;
    int r4 = t - bl * 40;
    float4 s = {0.f, 0.f, 0.f, 0.f};
    size_t base = ((size_t)bl * SEG) * 40 + r4;
#pragma unroll
    for (int seg = 0; seg < SEG; ++seg) {
      float4 v = fp4[base + (size_t)seg * 40];
      s.x += v.x; s.y += v.y; s.z += v.z; s.w += v.w;
    }
    *(float4*)&sred[bl][r4 * 4] = s;
  }
  __syncthreads();

  // expand weights to registers: wreg[j][ri][d], zero for j==c (static indexing)
  float wreg[8][2][3];
#pragma unroll
  for (int j = 0; j < 8; ++j) {
    int jj = j - (j > c ? 1 : 0);
    if (j == c) jj = 0;
#pragma unroll
    for (int ri = 0; ri < 2; ++ri)
#pragma unroll
      for (int d = 0; d < 3; ++d) {
        float v = swc[(c * 2 + p) * 42 + ri * 21 + jj * 3 + d];
        wreg[j][ri][d] = (j == c) ? 0.f : v;
      }
  }
  const float* wop = swout + p * 80 + c * 10;

  float o0, o1;
#pragma unroll
  for (int half = 0; half < 2; ++half) {
    float o = 0.f;
#pragma unroll
    for (int w = 0; w < WW; ++w) {
      float4 f0 = *(const float4*)&sred[b2][w * 16];
      float4 f1 = *(const float4*)&sred[b2][w * 16 + 4];
      float4 f2 = *(const float4*)&sred[b2][w * 16 + 8];
      float4 f3 = *(const float4*)&sred[b2][w * 16 + 12];
      float fv[16] = {f0.x, f0.y, f0.z, f0.w, f1.x, f1.y, f1.z, f1.w,
                      f2.x, f2.y, f2.z, f2.w, f3.x, f3.y, f3.z, f3.w};
      float nl0 = 0.f, nl1 = 0.f, nl2 = 0.f;
#pragma unroll
      for (int j = 0; j < 8; ++j) {
        float r  = fv[2 * j];
        float im = fv[2 * j + 1];
        float r2 = r * r, i2 = im * im;
        float pw0 = r + im;
        float pw1 = r2 + i2;
        float pw2 = r2 * r + i2 * im;
        nl0 += (pw0 * r) * wreg[j][0][0] + (pw0 * im) * wreg[j][1][0];
        nl1 += (pw1 * r) * wreg[j][0][1] + (pw1 * im) * wreg[j][1][1];
        nl2 += (pw2 * r) * wreg[j][0][2] + (pw2 * im) * wreg[j][1][2];
      }
      o += (nl0 + nl1 + nl2) * wop[w];
    }
    if (half == 0) {
      o0 = o;
      __syncthreads();   // done reading sred (phase A)
      // ---- stage phase B (b = 64..127) ----
      for (int t = tid; t < 64 * 40; t += 1024) {
        int bl = t / 40;
        int r4 = t - bl * 40;
        float4 s = {0.f, 0.f, 0.f, 0.f};
        size_t base = ((size_t)(64 + bl) * SEG) * 40 + r4;
#pragma unroll
        for (int seg = 0; seg < SEG; ++seg) {
          float4 v = fp4[base + (size_t)seg * 40];
          s.x += v.x; s.y += v.y; s.z += v.z; s.w += v.w;
        }
        *(float4*)&sred[bl][r4 * 4] = s;
      }
      __syncthreads();
    } else {
      o1 = o;
    }
  }

  // ---- BatchNorm: mean/var per c over 256 values (128 b x 2 p) ----
  float s  = o0 + o1;
  float sq = o0 * o0 + o1 * o1;
  s  += __shfl_xor(s, 1);   sq += __shfl_xor(sq, 1);    // p bit
  s  += __shfl_xor(s, 16);  sq += __shfl_xor(sq, 16);   // b2 bit 0
  s  += __shfl_xor(s, 32);  sq += __shfl_xor(sq, 32);   // b2 bit 1
  int wave = tid >> 6, lane = tid & 63;
  if ((lane & 0x31) == 0) { ps[wave][(lane >> 1) & 7] = s; qs[wave][(lane >> 1) & 7] = sq; }
  __syncthreads();
  if (tid < 8) {
    float S = 0.f, Q = 0.f;
#pragma unroll
    for (int k = 0; k < 16; ++k) { S += ps[k][tid]; Q += qs[k][tid]; }
    float mean = S * (1.0f / 256.0f);
    float var  = Q * (1.0f / 256.0f) - mean * mean;
    mv[tid] = mean;
    iv[tid] = gamma[tid] * rsqrtf(var + 1e-5f);
    bv[tid] = beta[tid];
  }
  __syncthreads();

  // out[tid] = (b2, c, p), out[tid+1024] = (b2+64, c, p)
  out[tid]        = (o0 - mv[c]) * iv[c] + bv[c];
  out[tid + 1024] = (o1 - mv[c]) * iv[c] + bv[c];
}

// ---------------------------------------------------------------------------
extern "C" void kernel_launch(void* const* d_in, const int* in_sizes, int n_in,
                              void* d_out, int out_size, void* d_ws, size_t ws_size,
                              hipStream_t stream) {
  const float* x   = (const float*)d_in[0];
  const float* wr  = (const float*)d_in[1];
  const float* wi  = (const float*)d_in[2];
  const float* wc  = (const float*)d_in[3];
  const float* wor = (const float*)d_in[4];
  const float* woi = (const float*)d_in[5];
  const float* gm  = (const float*)d_in[6];
  const float* bt  = (const float*)d_in[7];
  float* out = (float*)d_out;

  float* ws    = (float*)d_ws;
  float* w2    = ws;                                    // CC*LP*2 = 262272 f32
  float* fpart = w2 + (size_t)CC * LP * 2;              // B*SEG*160 = 163840 f32

  k_interleave<<<dim3((LP * CC + 255) / 256), dim3(256), 0, stream>>>(wr, wi, w2);
  k_fir<<<dim3((BB / BP) * SEG), dim3(512), 0, stream>>>(x, w2, fpart);
  k_final<<<dim3(1), dim3(1024), 0, stream>>>(fpart, wc, wor, woi, gm, bt, out);
}

// Round 4
// 48.576 us; speedup vs baseline: 1.7834x; 1.7834x over previous
//
#include <hip/hip_runtime.h>

#define BB 128
#define NN 16384
#define CC 8
#define WW 10
#define DD 3
#define LL 16375     // N - W + 1
#define LP 16392     // zero-padded weight length (covers l up to N-1)
#define SEG 8
#define CHLEN 64     // n's per thread
#define BPB 16       // b per k_nonlin block
#define ABLK (BB / BPB)

typedef float f2_t __attribute__((ext_vector_type(2)));

// ---------------------------------------------------------------------------
// K0: build w2t[l][c] = (wr[c,l], wi[c,l]) interleaved, zero-padded l in [LL,LP)
// ---------------------------------------------------------------------------
__global__ __launch_bounds__(256) void k_interleave(const float* __restrict__ wr,
                                                    const float* __restrict__ wi,
                                                    float* __restrict__ w2) {
  int idx = blockIdx.x * 256 + threadIdx.x;   // idx = l*8 + c
  if (idx >= LP * CC) return;
  int l = idx >> 3;
  int c = idx & 7;
  float a = 0.f, b = 0.f;
  if (l < LL) { a = wr[c * LL + l]; b = wi[c * LL + l]; }
  w2[2 * idx]     = a;
  w2[2 * idx + 1] = b;
}

// ---------------------------------------------------------------------------
// K1: main FIR. Grid = B*SEG blocks x 256 threads (round-2 structure).
// ONE change vs round 2: each 16-step group is split into a load phase
// (16 w-loads + 16 x-loads, independent, all-register static indexing) and a
// compute phase (320 FMAs), with a 9-element carry window prev[] holding the
// previous group's last weights. ~32 loads in flight per wave instead of ~2.
// ---------------------------------------------------------------------------
__global__ __launch_bounds__(256) void k_fir(const float* __restrict__ x,
                                             const float* __restrict__ w2,
                                             float* __restrict__ fpart) {
  int b   = blockIdx.x >> 3;
  int seg = blockIdx.x & 7;
  int tid = threadIdx.x;
  int c     = tid & 7;
  int chunk = tid >> 3;                        // 0..31
  int n0 = seg * (NN / SEG) + chunk * CHLEN;   // multiple of 16

  const f2_t* __restrict__ xp  = ((const f2_t*)x)  + (size_t)b * NN * CC + c; // xp[n*CC]
  const f2_t* __restrict__ wpt = ((const f2_t*)w2) + c;                        // wpt[l*CC]

  f2_t acc[WW];
#pragma unroll
  for (int w = 0; w < WW; ++w) acc[w] = (f2_t)0.f;

  // carry window: prev[k] holds weight at l = nb-9+k for the current group nb
  f2_t prev[9];
#pragma unroll
  for (int k = 0; k < 9; ++k) {
    int l = n0 - 9 + k;
    prev[k] = (l >= 0) ? wpt[(size_t)l * CC] : (f2_t)0.f;
  }

  for (int g = 0; g < CHLEN / 16; ++g) {
    int nb = n0 + g * 16;
    f2_t wv[16], xv[16];
    // ---- load phase: 32 independent loads ----
#pragma unroll
    for (int u = 0; u < 16; ++u) {
      wv[u] = wpt[(size_t)(nb + u) * CC];   // padded rows make l<LP safe
      xv[u] = xp[(size_t)(nb + u) * CC];
    }
    // ---- compute phase: 320 FMAs, all weight picks compile-time ----
#pragma unroll
    for (int u = 0; u < 16; ++u) {
#pragma unroll
      for (int w = 0; w < WW; ++w) {
        int idx = u - w;
        f2_t wt = (idx >= 0) ? wv[idx] : prev[idx + 9];
        acc[w][0] += xv[u][0] * wt[0];
        acc[w][1] += xv[u][1] * wt[1];
      }
    }
    // ---- carry: last 9 weights (l = nb+7 .. nb+15) ----
#pragma unroll
    for (int k = 0; k < 9; ++k) prev[k] = wv[7 + k];
  }

  // block reduction over the 32 chunks (round-2 epilogue, verbatim)
  __shared__ float red[256 * 20];
#pragma unroll
  for (int w = 0; w < WW; ++w) {
    red[tid * 20 + 2 * w]     = acc[w][0];
    red[tid * 20 + 2 * w + 1] = acc[w][1];
  }
  __syncthreads();
  if (tid < 160) {               // tid = w*16 + c*2 + ri
    int cc = (tid >> 1) & 7;
    int wv_ = tid >> 4;
    int ri = tid & 1;
    int k  = 2 * wv_ + ri;
    float s = 0.f;
    for (int ch = 0; ch < 32; ++ch) s += red[(ch * 8 + cc) * 20 + k];
    fpart[(size_t)blockIdx.x * 160 + tid] = s;
  }
}

// ---------------------------------------------------------------------------
// K2: nonlin + output projection. Grid = 8 blocks x 256 threads. (round 2)
// ---------------------------------------------------------------------------
__global__ __launch_bounds__(256) void k_nonlin(const float* __restrict__ fpart,
                                                const float* __restrict__ wc,
                                                const float* __restrict__ wor,
                                                const float* __restrict__ woi,
                                                float* __restrict__ oraw,
                                                float* __restrict__ part) {
  __shared__ float sred[BPB][164];   // seg-reduced rows [b][w*16 + c*2 + ri], padded
  __shared__ float swc[704];         // w_coeff (672 used)
  __shared__ float swout[160];       // [p][c][w]

  int tid = threadIdx.x;
  int blk = blockIdx.x;
  int b0 = blk * BPB;

  for (int i = tid; i < 672; i += 256) swc[i] = wc[i];
  if (tid < 80) swout[tid] = wor[tid];
  else if (tid < 160) swout[tid] = woi[tid - 80];

  // stage + seg-reduce fpart -> sred. fpart float4 layout: [(b*8+seg)][40]
  {
    const float4* fp4 = (const float4*)fpart;
    for (int o4 = tid; o4 < BPB * 40; o4 += 256) {
      int bl = o4 / 40;
      int r4 = o4 - bl * 40;
      float4 s = {0.f, 0.f, 0.f, 0.f};
      size_t base = ((size_t)(b0 + bl) * 8) * 40 + r4;
#pragma unroll
      for (int seg = 0; seg < 8; ++seg) {
        float4 v = fp4[base + (size_t)seg * 40];
        s.x += v.x; s.y += v.y; s.z += v.z; s.w += v.w;
      }
      int r = r4 * 4;
      sred[bl][r] = s.x; sred[bl][r + 1] = s.y; sred[bl][r + 2] = s.z; sred[bl][r + 3] = s.w;
    }
  }
  __syncthreads();

  int b = tid >> 4;
  int c = (tid >> 1) & 7;
  int p = tid & 1;

  // expand weights to registers: wreg[j][ri][d], zero for j==c (static indexing)
  float wreg[8][2][3];
#pragma unroll
  for (int j = 0; j < 8; ++j) {
    int jj = j - (j > c ? 1 : 0);
    if (j == c) jj = 0;                       // keep index in-bounds; value zeroed below
#pragma unroll
    for (int ri = 0; ri < 2; ++ri)
#pragma unroll
      for (int d = 0; d < 3; ++d) {
        float v = swc[(c * 2 + p) * 42 + ri * 21 + jj * 3 + d];
        wreg[j][ri][d] = (j == c) ? 0.f : v;
      }
  }

  float o = 0.f;
  const float* wop = swout + p * 80 + c * 10;
#pragma unroll
  for (int w = 0; w < WW; ++w) {
    float4 f0 = *(const float4*)&sred[b][w * 16];
    float4 f1 = *(const float4*)&sred[b][w * 16 + 4];
    float4 f2 = *(const float4*)&sred[b][w * 16 + 8];
    float4 f3 = *(const float4*)&sred[b][w * 16 + 12];
    float fv[16] = {f0.x, f0.y, f0.z, f0.w, f1.x, f1.y, f1.z, f1.w,
                    f2.x, f2.y, f2.z, f2.w, f3.x, f3.y, f3.z, f3.w};
    float nl0 = 0.f, nl1 = 0.f, nl2 = 0.f;
#pragma unroll
    for (int j = 0; j < 8; ++j) {
      float r  = fv[2 * j];
      float im = fv[2 * j + 1];
      float r2 = r * r, i2 = im * im;
      float pw0 = r + im;
      float pw1 = r2 + i2;
      float pw2 = r2 * r + i2 * im;
      nl0 += (pw0 * r) * wreg[j][0][0] + (pw0 * im) * wreg[j][1][0];
      nl1 += (pw1 * r) * wreg[j][0][1] + (pw1 * im) * wreg[j][1][1];
      nl2 += (pw2 * r) * wreg[j][0][2] + (pw2 * im) * wreg[j][1][2];
    }
    o += (nl0 + nl1 + nl2) * wop[w];
  }

  oraw[((size_t)(b0 + b) * CC + c) * 2 + p] = o;

  // per-(block, c) partial sums for BN
  __shared__ float sval[256], ssq[256];
  sval[tid] = o;
  ssq[tid]  = o * o;
  __syncthreads();
  if (tid < 8) {
    float S = 0.f, Q = 0.f;
#pragma unroll
    for (int k = 0; k < 32; ++k) {
      int t = (k >> 1) * 16 + tid * 2 + (k & 1);   // b=(k>>1), c=tid, p=(k&1)
      S += sval[t];
      Q += ssq[t];
    }
    part[(blk * 8 + tid) * 2 + 0] = S;
    part[(blk * 8 + tid) * 2 + 1] = Q;
  }
}

// ---------------------------------------------------------------------------
// K3: BatchNorm finalize. 1 block x 256 threads. (round 2)
// ---------------------------------------------------------------------------
__global__ __launch_bounds__(256) void k_bn(const float* __restrict__ oraw,
                                            const float* __restrict__ part,
                                            const float* __restrict__ gamma,
                                            const float* __restrict__ beta,
                                            float* __restrict__ out) {
  __shared__ float mv[8], iv[8], bv[8];
  int tid = threadIdx.x;
  if (tid < 8) {
    float S = 0.f, Q = 0.f;
#pragma unroll
    for (int blk = 0; blk < ABLK; ++blk) {
      S += part[(blk * 8 + tid) * 2 + 0];
      Q += part[(blk * 8 + tid) * 2 + 1];
    }
    float mean = S * (1.0f / 256.0f);
    float var  = Q * (1.0f / 256.0f) - mean * mean;
    mv[tid] = mean;
    iv[tid] = gamma[tid] * rsqrtf(var + 1e-5f);
    bv[tid] = beta[tid];
  }
  __syncthreads();
  for (int i = tid; i < BB * CC * 2; i += 256) {
    int c = (i >> 1) & 7;
    out[i] = (oraw[i] - mv[c]) * iv[c] + bv[c];
  }
}

// ---------------------------------------------------------------------------
extern "C" void kernel_launch(void* const* d_in, const int* in_sizes, int n_in,
                              void* d_out, int out_size, void* d_ws, size_t ws_size,
                              hipStream_t stream) {
  const float* x   = (const float*)d_in[0];
  const float* wr  = (const float*)d_in[1];
  const float* wi  = (const float*)d_in[2];
  const float* wc  = (const float*)d_in[3];
  const float* wor = (const float*)d_in[4];
  const float* woi = (const float*)d_in[5];
  const float* gm  = (const float*)d_in[6];
  const float* bt  = (const float*)d_in[7];
  float* out = (float*)d_out;

  float* ws    = (float*)d_ws;
  float* w2    = ws;                                    // CC*LP*2 = 262272 f32
  float* fpart = w2 + (size_t)CC * LP * 2;              // B*SEG*160 = 163840 f32
  float* oraw  = fpart + (size_t)BB * SEG * 160;        // 2048 f32
  float* part  = oraw + BB * CC * 2;                    // 128 f32

  k_interleave<<<dim3((LP * CC + 255) / 256), dim3(256), 0, stream>>>(wr, wi, w2);
  k_fir<<<dim3(BB * SEG), dim3(256), 0, stream>>>(x, w2, fpart);
  k_nonlin<<<dim3(ABLK), dim3(256), 0, stream>>>(fpart, wc, wor, woi, oraw, part);
  k_bn<<<dim3(1), dim3(256), 0, stream>>>(oraw, part, gm, bt, out);
}

// Round 5
// 46.196 us; speedup vs baseline: 1.8753x; 1.0515x over previous
//
#include <hip/hip_runtime.h>

#define BB 128
#define NN 16384
#define CC 8
#define WW 10
#define LL 16375      // N - W + 1
#define NT 512        // n's per block tile
#define NTILES (NN / NT)   // 32
#define BT 8          // b's per k_fir block
#define BTILES (BB / BT)   // 16
#define WSL (NT + 9)  // staged weight slots per channel (taps l = ntile-9 .. ntile+NT-1)
#define BPB 16        // b per k_nonlin block
#define ABLK (BB / BPB)

typedef float f2_t __attribute__((ext_vector_type(2)));

// ---------------------------------------------------------------------------
// K1: FIR, n-tiled with LDS-staged weights (read directly from wr/wi).
// Grid = BTILES*NTILES = 512 blocks x 256 threads.
// Block (bt, nt): stages w[l][c] for l in [ntile-9, ntile+NT) into LDS
// (zero-padded outside [0,LL)), then thread (c=tid&7, bsub=(tid>>3)&7,
// nh=tid>>6) walks 128 n's for batch b = bt*8+bsub, with a prev[9] carry
// window and per-16-group batched loads (x: global 8B; w: ds_read broadcast).
// Epilogue: LDS (aliased over weight buf) reduce over nh, write fpart[b][nt].
// ---------------------------------------------------------------------------
__global__ __launch_bounds__(256) void k_fir(const float* __restrict__ x,
                                             const float* __restrict__ wr,
                                             const float* __restrict__ wi,
                                             float* __restrict__ fpart) {
  __shared__ float smem[WSL * CC * 2];   // 33.3 KB; weights, later aliased as reduce buf
  f2_t* sw2 = (f2_t*)smem;

  int nt = blockIdx.x & (NTILES - 1);
  int bt = blockIdx.x >> 5;              // NTILES = 32
  int tid = threadIdx.x;
  int ntile = nt * NT;
  int l0 = ntile - 9;

  // ---- stage weights: sw2[c*WSL + j] = (wr[c][l0+j], wi[c][l0+j]) or 0 ----
  {
    int cs = tid >> 5;                   // 8 channel groups x 32 lanes
    int jj = tid & 31;
    for (int j = jj; j < WSL; j += 32) { // coalesced 128B row reads
      int l = l0 + j;
      float a = 0.f, bb = 0.f;
      if (l >= 0 && l < LL) { a = wr[cs * LL + l]; bb = wi[cs * LL + l]; }
      f2_t v; v[0] = a; v[1] = bb;
      sw2[cs * WSL + j] = v;
    }
  }
  __syncthreads();

  int c    = tid & 7;
  int bsub = (tid >> 3) & 7;
  int nh   = tid >> 6;                   // 0..3, quarter of the n-tile
  int b    = bt * BT + bsub;

  const f2_t* __restrict__ xp = ((const f2_t*)x) + ((size_t)b * NN + ntile + nh * 128) * CC + c;
  const f2_t* wp = sw2 + c * WSL + nh * 128 + 9;   // wp[k] = tap at n = nstart + k

  f2_t acc[WW];
#pragma unroll
  for (int w = 0; w < WW; ++w) acc[w] = (f2_t)0.f;

  // carry window: prev[k] = tap at l = nstart - 9 + k (zero-padded in LDS)
  f2_t prev[9];
#pragma unroll
  for (int k = 0; k < 9; ++k) prev[k] = wp[k - 9];

  for (int g = 0; g < 8; ++g) {
    f2_t wv[16], xv[16];
#pragma unroll
    for (int u = 0; u < 16; ++u) {
      wv[u] = wp[g * 16 + u];                       // ds_read_b64, bsub-broadcast
      xv[u] = xp[(size_t)(g * 16 + u) * CC];        // global 8B, 8x64B clusters/wave
    }
#pragma unroll
    for (int u = 0; u < 16; ++u) {
#pragma unroll
      for (int w = 0; w < WW; ++w) {
        int idx = u - w;
        f2_t wt = (idx >= 0) ? wv[idx] : prev[idx + 9];
        acc[w][0] += xv[u][0] * wt[0];
        acc[w][1] += xv[u][1] * wt[1];
      }
    }
#pragma unroll
    for (int k = 0; k < 9; ++k) prev[k] = wv[7 + k];
  }

  __syncthreads();                       // all weight reads done; alias smem as reduce buf
  float* red = smem;                     // [nh*8 + bsub][160], 5120 floats
  int rb = (nh * 8 + bsub) * 160 + c * 2;
#pragma unroll
  for (int w = 0; w < WW; ++w) {
    red[rb + w * 16]     = acc[w][0];
    red[rb + w * 16 + 1] = acc[w][1];
  }
  __syncthreads();
  for (int t = tid; t < BT * 160; t += 256) {
    int bs = t / 160;
    int r  = t - bs * 160;
    float s = red[(0 * 8 + bs) * 160 + r] + red[(1 * 8 + bs) * 160 + r]
            + red[(2 * 8 + bs) * 160 + r] + red[(3 * 8 + bs) * 160 + r];
    fpart[((size_t)(bt * BT + bs) * NTILES + nt) * 160 + r] = s;
  }
}

// ---------------------------------------------------------------------------
// K2: nonlin + output projection. Grid = 8 blocks x 256 threads.
// Reduces the NTILES partials during the float4 staging pass.
// ---------------------------------------------------------------------------
__global__ __launch_bounds__(256) void k_nonlin(const float* __restrict__ fpart,
                                                const float* __restrict__ wc,
                                                const float* __restrict__ wor,
                                                const float* __restrict__ woi,
                                                float* __restrict__ oraw,
                                                float* __restrict__ part) {
  __shared__ float sred[BPB][164];   // tile-reduced rows [b][w*16 + c*2 + ri], padded
  __shared__ float swc[704];         // w_coeff (672 used)
  __shared__ float swout[160];       // [p][c][w]

  int tid = threadIdx.x;
  int blk = blockIdx.x;
  int b0 = blk * BPB;

  for (int i = tid; i < 672; i += 256) swc[i] = wc[i];
  if (tid < 80) swout[tid] = wor[tid];
  else if (tid < 160) swout[tid] = woi[tid - 80];

  // stage + tile-reduce fpart -> sred. fpart float4 layout: [(b*NTILES+nt)][40]
  {
    const float4* fp4 = (const float4*)fpart;
    for (int o4 = tid; o4 < BPB * 40; o4 += 256) {
      int bl = o4 / 40;
      int r4 = o4 - bl * 40;
      float4 s = {0.f, 0.f, 0.f, 0.f};
      size_t base = ((size_t)(b0 + bl) * NTILES) * 40 + r4;
#pragma unroll
      for (int seg = 0; seg < NTILES; ++seg) {
        float4 v = fp4[base + (size_t)seg * 40];
        s.x += v.x; s.y += v.y; s.z += v.z; s.w += v.w;
      }
      int r = r4 * 4;
      sred[bl][r] = s.x; sred[bl][r + 1] = s.y; sred[bl][r + 2] = s.z; sred[bl][r + 3] = s.w;
    }
  }
  __syncthreads();

  int b = tid >> 4;
  int c = (tid >> 1) & 7;
  int p = tid & 1;

  // expand weights to registers: wreg[j][ri][d], zero for j==c (static indexing)
  float wreg[8][2][3];
#pragma unroll
  for (int j = 0; j < 8; ++j) {
    int jj = j - (j > c ? 1 : 0);
    if (j == c) jj = 0;                       // keep index in-bounds; value zeroed below
#pragma unroll
    for (int ri = 0; ri < 2; ++ri)
#pragma unroll
      for (int d = 0; d < 3; ++d) {
        float v = swc[(c * 2 + p) * 42 + ri * 21 + jj * 3 + d];
        wreg[j][ri][d] = (j == c) ? 0.f : v;
      }
  }

  float o = 0.f;
  const float* wop = swout + p * 80 + c * 10;
#pragma unroll
  for (int w = 0; w < WW; ++w) {
    float4 f0 = *(const float4*)&sred[b][w * 16];
    float4 f1 = *(const float4*)&sred[b][w * 16 + 4];
    float4 f2 = *(const float4*)&sred[b][w * 16 + 8];
    float4 f3 = *(const float4*)&sred[b][w * 16 + 12];
    float fv[16] = {f0.x, f0.y, f0.z, f0.w, f1.x, f1.y, f1.z, f1.w,
                    f2.x, f2.y, f2.z, f2.w, f3.x, f3.y, f3.z, f3.w};
    float nl0 = 0.f, nl1 = 0.f, nl2 = 0.f;
#pragma unroll
    for (int j = 0; j < 8; ++j) {
      float r  = fv[2 * j];
      float im = fv[2 * j + 1];
      float r2 = r * r, i2 = im * im;
      float pw0 = r + im;
      float pw1 = r2 + i2;
      float pw2 = r2 * r + i2 * im;
      nl0 += (pw0 * r) * wreg[j][0][0] + (pw0 * im) * wreg[j][1][0];
      nl1 += (pw1 * r) * wreg[j][0][1] + (pw1 * im) * wreg[j][1][1];
      nl2 += (pw2 * r) * wreg[j][0][2] + (pw2 * im) * wreg[j][1][2];
    }
    o += (nl0 + nl1 + nl2) * wop[w];
  }

  oraw[((size_t)(b0 + b) * CC + c) * 2 + p] = o;

  // per-(block, c) partial sums for BN
  __shared__ float sval[256], ssq[256];
  sval[tid] = o;
  ssq[tid]  = o * o;
  __syncthreads();
  if (tid < 8) {
    float S = 0.f, Q = 0.f;
#pragma unroll
    for (int k = 0; k < 32; ++k) {
      int t = (k >> 1) * 16 + tid * 2 + (k & 1);   // b=(k>>1), c=tid, p=(k&1)
      S += sval[t];
      Q += ssq[t];
    }
    part[(blk * 8 + tid) * 2 + 0] = S;
    part[(blk * 8 + tid) * 2 + 1] = Q;
  }
}

// ---------------------------------------------------------------------------
// K3: BatchNorm finalize. 1 block x 256 threads.
// ---------------------------------------------------------------------------
__global__ __launch_bounds__(256) void k_bn(const float* __restrict__ oraw,
                                            const float* __restrict__ part,
                                            const float* __restrict__ gamma,
                                            const float* __restrict__ beta,
                                            float* __restrict__ out) {
  __shared__ float mv[8], iv[8], bv[8];
  int tid = threadIdx.x;
  if (tid < 8) {
    float S = 0.f, Q = 0.f;
#pragma unroll
    for (int blk = 0; blk < ABLK; ++blk) {
      S += part[(blk * 8 + tid) * 2 + 0];
      Q += part[(blk * 8 + tid) * 2 + 1];
    }
    float mean = S * (1.0f / 256.0f);
    float var  = Q * (1.0f / 256.0f) - mean * mean;
    mv[tid] = mean;
    iv[tid] = gamma[tid] * rsqrtf(var + 1e-5f);
    bv[tid] = beta[tid];
  }
  __syncthreads();
  for (int i = tid; i < BB * CC * 2; i += 256) {
    int c = (i >> 1) & 7;
    out[i] = (oraw[i] - mv[c]) * iv[c] + bv[c];
  }
}

// ---------------------------------------------------------------------------
extern "C" void kernel_launch(void* const* d_in, const int* in_sizes, int n_in,
                              void* d_out, int out_size, void* d_ws, size_t ws_size,
                              hipStream_t stream) {
  const float* x   = (const float*)d_in[0];
  const float* wr  = (const float*)d_in[1];
  const float* wi  = (const float*)d_in[2];
  const float* wc  = (const float*)d_in[3];
  const float* wor = (const float*)d_in[4];
  const float* woi = (const float*)d_in[5];
  const float* gm  = (const float*)d_in[6];
  const float* bt  = (const float*)d_in[7];
  float* out = (float*)d_out;

  float* ws    = (float*)d_ws;
  float* fpart = ws;                                    // B*NTILES*160 = 655360 f32 (2.62 MB)
  float* oraw  = fpart + (size_t)BB * NTILES * 160;     // 2048 f32
  float* part  = oraw + BB * CC * 2;                    // 128 f32

  k_fir<<<dim3(BTILES * NTILES), dim3(256), 0, stream>>>(x, wr, wi, fpart);
  k_nonlin<<<dim3(ABLK), dim3(256), 0, stream>>>(fpart, wc, wor, woi, oraw, part);
  k_bn<<<dim3(1), dim3(256), 0, stream>>>(oraw, part, gm, bt, out);
}

// Round 6
// 45.518 us; speedup vs baseline: 1.9032x; 1.0149x over previous
//
#include <hip/hip_runtime.h>

#define BB 128
#define NN 16384
#define CC 8
#define WW 10
#define LL 16375      // N - W + 1
#define NT 512        // n's per block tile
#define NTILES (NN / NT)   // 32
#define BT 4          // b's per k_fir block
#define BTILES (BB / BT)   // 32
#define WSL (NT + 9)  // 521 staged taps per channel (l = ntile-9 .. ntile+NT-1)
#define BPB 16        // b per k_nonlin block
#define ABLK (BB / BPB)

typedef float f4_t __attribute__((ext_vector_type(4)));

// ---------------------------------------------------------------------------
// K1: FIR with float4 (16B/lane) x loads. Grid = BTILES*NTILES = 1024 blocks
// x 256 threads. Thread (c2=tid&3, bsub=(tid>>2)&3, nh=tid>>4) owns channel
// pair {2c2, 2c2+1} of batch bt*4+bsub for 32 n's. Weights staged in LDS as
// float4 rows matching the x layout: sw[j][c2] = {wr,wi}x{2c2,2c2+1} at tap
// l0+j, zero-padded outside [0,LL). 16-slot modular register window with the
// clobber-safe reload schedule (slot u+7 refilled after iteration u).
// ---------------------------------------------------------------------------
__global__ __launch_bounds__(256) void k_fir(const float* __restrict__ x,
                                             const float* __restrict__ wr,
                                             const float* __restrict__ wi,
                                             float* __restrict__ fpart) {
  __shared__ float smem[WSL * 16 + 16];   // 33.4 KB (f4 view: WSL*4); reused for reduce
  f4_t* sw = (f4_t*)smem;

  int nt = blockIdx.x & (NTILES - 1);
  int bt = blockIdx.x >> 5;               // NTILES = 32
  int tid = threadIdx.x;
  int ntile = nt * NT;
  int l0 = ntile - 9;

  // ---- stage weights: sw[j*4 + c2] = {wr[2c2][l], wi[2c2][l], wr[2c2+1][l], wi[2c2+1][l]} ----
  {
    int c2s = tid >> 6;                    // 4 channel-pair groups x 64 lanes
    int ca = 2 * c2s, cb = 2 * c2s + 1;
    for (int j = tid & 63; j < WSL; j += 64) {   // coalesced along l
      int l = l0 + j;
      f4_t v = (f4_t)0.f;
      if (l >= 0 && l < LL) {
        v[0] = wr[(size_t)ca * LL + l];
        v[1] = wi[(size_t)ca * LL + l];
        v[2] = wr[(size_t)cb * LL + l];
        v[3] = wi[(size_t)cb * LL + l];
      }
      sw[j * 4 + c2s] = v;
    }
  }
  __syncthreads();

  int c2   = tid & 3;
  int bsub = (tid >> 2) & 3;
  int nh   = tid >> 4;                    // 0..15, 32-n slice
  int b    = bt * BT + bsub;
  int n0   = ntile + nh * 32;

  const f4_t* __restrict__ xp = ((const f4_t*)x) + ((size_t)b * NN + n0) * 4 + c2;
  const f4_t* swp = sw + (nh * 32 + 9) * 4 + c2;   // swp[4*t] = tap at n0 + t

  f4_t acc[WW];
#pragma unroll
  for (int w = 0; w < WW; ++w) acc[w] = (f4_t)0.f;

  f4_t wv[16];
  // preload slots 7..15 = taps n0-9 .. n0-1 (zero-padded in LDS)
#pragma unroll
  for (int k = 0; k < 9; ++k) wv[7 + k] = swp[4 * (k - 9)];

#pragma unroll
  for (int g = 0; g < 2; ++g) {
    // load slots 0..6 = taps nb .. nb+6 (their old contents are dead)
#pragma unroll
    for (int j = 0; j < 7; ++j) wv[j] = swp[4 * (16 * g + j)];
#pragma unroll
    for (int u = 0; u < 16; ++u) {
      f4_t xv = xp[(size_t)(16 * g + u) * 4];
#pragma unroll
      for (int w = 0; w < WW; ++w) {
        f4_t wt = wv[(u - w + 16) & 15];
        acc[w][0] += xv[0] * wt[0];
        acc[w][1] += xv[1] * wt[1];
        acc[w][2] += xv[2] * wt[2];
        acc[w][3] += xv[3] * wt[3];
      }
      // slot u+7 (old tap nb-9+u) is last consumed at iteration u; refill now
      if (u <= 8) wv[u + 7] = swp[4 * (16 * g + u + 7)];
    }
  }

  // ---- reduce over nh bits 0,1 (= lane bits 4,5) in-register ----
#pragma unroll
  for (int w = 0; w < WW; ++w)
#pragma unroll
    for (int e = 0; e < 4; ++e) {
      acc[w][e] += __shfl_xor(acc[w][e], 16);
      acc[w][e] += __shfl_xor(acc[w][e], 32);
    }

  __syncthreads();                        // weight reads done; alias smem as reduce buf
  int wave = tid >> 6, lane = tid & 63;
  if (lane < 16) {                        // lane = c2 + 4*bsub
#pragma unroll
    for (int w = 0; w < WW; ++w)
      *(f4_t*)&smem[(wave * 16 + lane) * 40 + w * 4] = acc[w];
  }
  __syncthreads();
  // final: sum the 4 waves (nh bits 2,3), write fpart[b][nt][160], r = w*16+c*2+ri
  for (int t = tid; t < BT * 160; t += 256) {
    int bs = t / 160;
    int r  = t - bs * 160;
    int w  = r >> 4;
    int cc = (r >> 1) & 7;
    int ri = r & 1;
    int ln = (cc >> 1) + 4 * bs;
    int e  = (cc & 1) * 2 + ri;
    float s = 0.f;
#pragma unroll
    for (int wv_ = 0; wv_ < 4; ++wv_) s += smem[(wv_ * 16 + ln) * 40 + w * 4 + e];
    fpart[((size_t)(bt * BT + bs) * NTILES + nt) * 160 + r] = s;
  }
}

// ---------------------------------------------------------------------------
// K2: nonlin + output projection. Grid = 8 blocks x 256 threads. (round 5)
// ---------------------------------------------------------------------------
__global__ __launch_bounds__(256) void k_nonlin(const float* __restrict__ fpart,
                                                const float* __restrict__ wc,
                                                const float* __restrict__ wor,
                                                const float* __restrict__ woi,
                                                float* __restrict__ oraw,
                                                float* __restrict__ part) {
  __shared__ float sred[BPB][164];   // tile-reduced rows [b][w*16 + c*2 + ri], padded
  __shared__ float swc[704];         // w_coeff (672 used)
  __shared__ float swout[160];       // [p][c][w]

  int tid = threadIdx.x;
  int blk = blockIdx.x;
  int b0 = blk * BPB;

  for (int i = tid; i < 672; i += 256) swc[i] = wc[i];
  if (tid < 80) swout[tid] = wor[tid];
  else if (tid < 160) swout[tid] = woi[tid - 80];

  // stage + tile-reduce fpart -> sred. fpart float4 layout: [(b*NTILES+nt)][40]
  {
    const float4* fp4 = (const float4*)fpart;
    for (int o4 = tid; o4 < BPB * 40; o4 += 256) {
      int bl = o4 / 40;
      int r4 = o4 - bl * 40;
      float4 s = {0.f, 0.f, 0.f, 0.f};
      size_t base = ((size_t)(b0 + bl) * NTILES) * 40 + r4;
#pragma unroll
      for (int seg = 0; seg < NTILES; ++seg) {
        float4 v = fp4[base + (size_t)seg * 40];
        s.x += v.x; s.y += v.y; s.z += v.z; s.w += v.w;
      }
      int r = r4 * 4;
      sred[bl][r] = s.x; sred[bl][r + 1] = s.y; sred[bl][r + 2] = s.z; sred[bl][r + 3] = s.w;
    }
  }
  __syncthreads();

  int b = tid >> 4;
  int c = (tid >> 1) & 7;
  int p = tid & 1;

  // expand weights to registers: wreg[j][ri][d], zero for j==c (static indexing)
  float wreg[8][2][3];
#pragma unroll
  for (int j = 0; j < 8; ++j) {
    int jj = j - (j > c ? 1 : 0);
    if (j == c) jj = 0;                       // keep index in-bounds; value zeroed below
#pragma unroll
    for (int ri = 0; ri < 2; ++ri)
#pragma unroll
      for (int d = 0; d < 3; ++d) {
        float v = swc[(c * 2 + p) * 42 + ri * 21 + jj * 3 + d];
        wreg[j][ri][d] = (j == c) ? 0.f : v;
      }
  }

  float o = 0.f;
  const float* wop = swout + p * 80 + c * 10;
#pragma unroll
  for (int w = 0; w < WW; ++w) {
    float4 f0 = *(const float4*)&sred[b][w * 16];
    float4 f1 = *(const float4*)&sred[b][w * 16 + 4];
    float4 f2 = *(const float4*)&sred[b][w * 16 + 8];
    float4 f3 = *(const float4*)&sred[b][w * 16 + 12];
    float fv[16] = {f0.x, f0.y, f0.z, f0.w, f1.x, f1.y, f1.z, f1.w,
                    f2.x, f2.y, f2.z, f2.w, f3.x, f3.y, f3.z, f3.w};
    float nl0 = 0.f, nl1 = 0.f, nl2 = 0.f;
#pragma unroll
    for (int j = 0; j < 8; ++j) {
      float r  = fv[2 * j];
      float im = fv[2 * j + 1];
      float r2 = r * r, i2 = im * im;
      float pw0 = r + im;
      float pw1 = r2 + i2;
      float pw2 = r2 * r + i2 * im;
      nl0 += (pw0 * r) * wreg[j][0][0] + (pw0 * im) * wreg[j][1][0];
      nl1 += (pw1 * r) * wreg[j][0][1] + (pw1 * im) * wreg[j][1][1];
      nl2 += (pw2 * r) * wreg[j][0][2] + (pw2 * im) * wreg[j][1][2];
    }
    o += (nl0 + nl1 + nl2) * wop[w];
  }

  oraw[((size_t)(b0 + b) * CC + c) * 2 + p] = o;

  // per-(block, c) partial sums for BN
  __shared__ float sval[256], ssq[256];
  sval[tid] = o;
  ssq[tid]  = o * o;
  __syncthreads();
  if (tid < 8) {
    float S = 0.f, Q = 0.f;
#pragma unroll
    for (int k = 0; k < 32; ++k) {
      int t = (k >> 1) * 16 + tid * 2 + (k & 1);   // b=(k>>1), c=tid, p=(k&1)
      S += sval[t];
      Q += ssq[t];
    }
    part[(blk * 8 + tid) * 2 + 0] = S;
    part[(blk * 8 + tid) * 2 + 1] = Q;
  }
}

// ---------------------------------------------------------------------------
// K3: BatchNorm finalize. 1 block x 256 threads. (round 5)
// ---------------------------------------------------------------------------
__global__ __launch_bounds__(256) void k_bn(const float* __restrict__ oraw,
                                            const float* __restrict__ part,
                                            const float* __restrict__ gamma,
                                            const float* __restrict__ beta,
                                            float* __restrict__ out) {
  __shared__ float mv[8], iv[8], bv[8];
  int tid = threadIdx.x;
  if (tid < 8) {
    float S = 0.f, Q = 0.f;
#pragma unroll
    for (int blk = 0; blk < ABLK; ++blk) {
      S += part[(blk * 8 + tid) * 2 + 0];
      Q += part[(blk * 8 + tid) * 2 + 1];
    }
    float mean = S * (1.0f / 256.0f);
    float var  = Q * (1.0f / 256.0f) - mean * mean;
    mv[tid] = mean;
    iv[tid] = gamma[tid] * rsqrtf(var + 1e-5f);
    bv[tid] = beta[tid];
  }
  __syncthreads();
  for (int i = tid; i < BB * CC * 2; i += 256) {
    int c = (i >> 1) & 7;
    out[i] = (oraw[i] - mv[c]) * iv[c] + bv[c];
  }
}

// ---------------------------------------------------------------------------
extern "C" void kernel_launch(void* const* d_in, const int* in_sizes, int n_in,
                              void* d_out, int out_size, void* d_ws, size_t ws_size,
                              hipStream_t stream) {
  const float* x   = (const float*)d_in[0];
  const float* wr  = (const float*)d_in[1];
  const float* wi  = (const float*)d_in[2];
  const float* wc  = (const float*)d_in[3];
  const float* wor = (const float*)d_in[4];
  const float* woi = (const float*)d_in[5];
  const float* gm  = (const float*)d_in[6];
  const float* bt  = (const float*)d_in[7];
  float* out = (float*)d_out;

  float* ws    = (float*)d_ws;
  float* fpart = ws;                                    // B*NTILES*160 = 655360 f32 (2.62 MB)
  float* oraw  = fpart + (size_t)BB * NTILES * 160;     // 2048 f32
  float* part  = oraw + BB * CC * 2;                    // 128 f32

  k_fir<<<dim3(BTILES * NTILES), dim3(256), 0, stream>>>(x, wr, wi, fpart);
  k_nonlin<<<dim3(ABLK), dim3(256), 0, stream>>>(fpart, wc, wor, woi, oraw, part);
  k_bn<<<dim3(1), dim3(256), 0, stream>>>(oraw, part, gm, bt, out);
}

// Round 7
// 45.245 us; speedup vs baseline: 1.9147x; 1.0061x over previous
//
#include <hip/hip_runtime.h>

#define BB 128
#define NN 16384
#define CC 8
#define WW 10
#define LL 16375      // N - W + 1
#define NT 512        // n's per block tile
#define NTILES (NN / NT)   // 32
#define BT 4          // b's per k_fir block
#define BTILES (BB / BT)   // 32
#define WSL (NT + 9)  // 521 staged taps per channel
#define BPB 2         // b per k_nonlin block
#define ABLK (BB / BPB)    // 64

typedef float f4_t __attribute__((ext_vector_type(4)));

// ---------------------------------------------------------------------------
// K1: FIR — byte-identical to round 6 (known-good, absmax 0.0) + cnt reset.
// ---------------------------------------------------------------------------
__global__ __launch_bounds__(256) void k_fir(const float* __restrict__ x,
                                             const float* __restrict__ wr,
                                             const float* __restrict__ wi,
                                             float* __restrict__ fpart,
                                             unsigned int* __restrict__ cnt) {
  if (blockIdx.x == 0 && threadIdx.x == 0) *cnt = 0u;   // reset for k_nonlin's last-block detect

  __shared__ float smem[WSL * 16 + 16];   // 33.4 KB; weights, later aliased as reduce buf
  f4_t* sw = (f4_t*)smem;

  int nt = blockIdx.x & (NTILES - 1);
  int bt = blockIdx.x >> 5;               // NTILES = 32
  int tid = threadIdx.x;
  int ntile = nt * NT;
  int l0 = ntile - 9;

  // ---- stage weights: sw[j*4 + c2] = {wr[2c2][l], wi[2c2][l], wr[2c2+1][l], wi[2c2+1][l]} ----
  {
    int c2s = tid >> 6;                    // 4 channel-pair groups x 64 lanes
    int ca = 2 * c2s, cb = 2 * c2s + 1;
    for (int j = tid & 63; j < WSL; j += 64) {   // coalesced along l
      int l = l0 + j;
      f4_t v = (f4_t)0.f;
      if (l >= 0 && l < LL) {
        v[0] = wr[(size_t)ca * LL + l];
        v[1] = wi[(size_t)ca * LL + l];
        v[2] = wr[(size_t)cb * LL + l];
        v[3] = wi[(size_t)cb * LL + l];
      }
      sw[j * 4 + c2s] = v;
    }
  }
  __syncthreads();

  int c2   = tid & 3;
  int bsub = (tid >> 2) & 3;
  int nh   = tid >> 4;                    // 0..15, 32-n slice
  int b    = bt * BT + bsub;
  int n0   = ntile + nh * 32;

  const f4_t* __restrict__ xp = ((const f4_t*)x) + ((size_t)b * NN + n0) * 4 + c2;
  const f4_t* swp = sw + (nh * 32 + 9) * 4 + c2;   // swp[4*t] = tap at n0 + t

  f4_t acc[WW];
#pragma unroll
  for (int w = 0; w < WW; ++w) acc[w] = (f4_t)0.f;

  f4_t wv[16];
  // preload slots 7..15 = taps n0-9 .. n0-1 (zero-padded in LDS)
#pragma unroll
  for (int k = 0; k < 9; ++k) wv[7 + k] = swp[4 * (k - 9)];

#pragma unroll
  for (int g = 0; g < 2; ++g) {
    // load slots 0..6 = taps nb .. nb+6 (their old contents are dead)
#pragma unroll
    for (int j = 0; j < 7; ++j) wv[j] = swp[4 * (16 * g + j)];
#pragma unroll
    for (int u = 0; u < 16; ++u) {
      f4_t xv = xp[(size_t)(16 * g + u) * 4];
#pragma unroll
      for (int w = 0; w < WW; ++w) {
        f4_t wt = wv[(u - w + 16) & 15];
        acc[w][0] += xv[0] * wt[0];
        acc[w][1] += xv[1] * wt[1];
        acc[w][2] += xv[2] * wt[2];
        acc[w][3] += xv[3] * wt[3];
      }
      // slot u+7 (old tap nb-9+u) is last consumed at iteration u; refill now
      if (u <= 8) wv[u + 7] = swp[4 * (16 * g + u + 7)];
    }
  }

  // ---- reduce over nh bits 0,1 (= lane bits 4,5) in-register ----
#pragma unroll
  for (int w = 0; w < WW; ++w)
#pragma unroll
    for (int e = 0; e < 4; ++e) {
      acc[w][e] += __shfl_xor(acc[w][e], 16);
      acc[w][e] += __shfl_xor(acc[w][e], 32);
    }

  __syncthreads();                        // weight reads done; alias smem as reduce buf
  int wave = tid >> 6, lane = tid & 63;
  if (lane < 16) {                        // lane = c2 + 4*bsub
#pragma unroll
    for (int w = 0; w < WW; ++w)
      *(f4_t*)&smem[(wave * 16 + lane) * 40 + w * 4] = acc[w];
  }
  __syncthreads();
  // final: sum the 4 waves (nh bits 2,3), write fpart[b][nt][160], r = w*16+c*2+ri
  for (int t = tid; t < BT * 160; t += 256) {
    int bs = t / 160;
    int r  = t - bs * 160;
    int w  = r >> 4;
    int cc = (r >> 1) & 7;
    int ri = r & 1;
    int ln = (cc >> 1) + 4 * bs;
    int e  = (cc & 1) * 2 + ri;
    float s = 0.f;
#pragma unroll
    for (int wv_ = 0; wv_ < 4; ++wv_) s += smem[(wv_ * 16 + ln) * 40 + w * 4 + e];
    fpart[((size_t)(bt * BT + bs) * NTILES + nt) * 160 + r] = s;
  }
}

// ---------------------------------------------------------------------------
// K2: nonlin + projection + fused BatchNorm. Grid = 64 blocks x 256 threads.
// Each block: 2 b's. Stage+tile-reduce fpart (80 rows, 32 unrolled loads each),
// compute o for (b2, c, p) on threads 0..31, write oraw + BN partials, then
// the LAST block (atomic counter) computes stats and normalizes all outputs.
// ---------------------------------------------------------------------------
__global__ __launch_bounds__(256) void k_nonlin(const float* __restrict__ fpart,
                                                const float* __restrict__ wc,
                                                const float* __restrict__ wor,
                                                const float* __restrict__ woi,
                                                const float* __restrict__ gamma,
                                                const float* __restrict__ beta,
                                                float* __restrict__ oraw,
                                                float* __restrict__ part,
                                                unsigned int* __restrict__ cnt,
                                                float* __restrict__ out) {
  __shared__ float sred[BPB][164];   // tile-reduced rows [b][w*16 + c*2 + ri]
  __shared__ float swc[672];
  __shared__ float swout[160];       // [p][c][w]

  int tid = threadIdx.x;
  int blk = blockIdx.x;
  int b0 = blk * BPB;

  for (int i = tid; i < 672; i += 256) swc[i] = wc[i];
  if (tid < 80) swout[tid] = wor[tid];
  else if (tid < 160) swout[tid] = woi[tid - 80];

  // stage + tile-reduce fpart -> sred: 80 rows, one per thread
  if (tid < BPB * 40) {
    int bl = tid / 40;
    int r4 = tid - bl * 40;
    const float4* fp4 = (const float4*)fpart;
    float4 s = {0.f, 0.f, 0.f, 0.f};
    size_t base = ((size_t)(b0 + bl) * NTILES) * 40 + r4;
#pragma unroll
    for (int seg = 0; seg < NTILES; ++seg) {
      float4 v = fp4[base + (size_t)seg * 40];
      s.x += v.x; s.y += v.y; s.z += v.z; s.w += v.w;
    }
    int r = r4 * 4;
    sred[bl][r] = s.x; sred[bl][r + 1] = s.y; sred[bl][r + 2] = s.z; sred[bl][r + 3] = s.w;
  }
  __syncthreads();

  if (tid < 32) {
    int bl = tid >> 4;                 // 0..1
    int c  = (tid >> 1) & 7;
    int p  = tid & 1;

    // expand weights: wreg[j][ri][d], zero for j==c (static indexing)
    float wreg[8][2][3];
#pragma unroll
    for (int j = 0; j < 8; ++j) {
      int jj = j - (j > c ? 1 : 0);
      if (j == c) jj = 0;
#pragma unroll
      for (int ri = 0; ri < 2; ++ri)
#pragma unroll
        for (int d = 0; d < 3; ++d) {
          float v = swc[(c * 2 + p) * 42 + ri * 21 + jj * 3 + d];
          wreg[j][ri][d] = (j == c) ? 0.f : v;
        }
    }

    float o = 0.f;
    const float* wop = swout + p * 80 + c * 10;
#pragma unroll
    for (int w = 0; w < WW; ++w) {
      float4 f0 = *(const float4*)&sred[bl][w * 16];
      float4 f1 = *(const float4*)&sred[bl][w * 16 + 4];
      float4 f2 = *(const float4*)&sred[bl][w * 16 + 8];
      float4 f3 = *(const float4*)&sred[bl][w * 16 + 12];
      float fv[16] = {f0.x, f0.y, f0.z, f0.w, f1.x, f1.y, f1.z, f1.w,
                      f2.x, f2.y, f2.z, f2.w, f3.x, f3.y, f3.z, f3.w};
      float nl0 = 0.f, nl1 = 0.f, nl2 = 0.f;
#pragma unroll
      for (int j = 0; j < 8; ++j) {
        float r  = fv[2 * j];
        float im = fv[2 * j + 1];
        float r2 = r * r, i2 = im * im;
        float pw0 = r + im;
        float pw1 = r2 + i2;
        float pw2 = r2 * r + i2 * im;
        nl0 += (pw0 * r) * wreg[j][0][0] + (pw0 * im) * wreg[j][1][0];
        nl1 += (pw1 * r) * wreg[j][0][1] + (pw1 * im) * wreg[j][1][1];
        nl2 += (pw2 * r) * wreg[j][0][2] + (pw2 * im) * wreg[j][1][2];
      }
      o += (nl0 + nl1 + nl2) * wop[w];
    }

    oraw[((size_t)(b0 + bl) * CC + c) * 2 + p] = o;

    // per-block BN partials: sum over p (lane bit 0) and bl (lane bit 4)
    float s = o, q = o * o;
    s += __shfl_xor(s, 1);  q += __shfl_xor(q, 1);
    s += __shfl_xor(s, 16); q += __shfl_xor(q, 16);
    if ((tid & 17) == 0) {             // p==0 && bl==0 -> tid = c*2
      part[blk * 16 + c * 2 + 0] = s;
      part[blk * 16 + c * 2 + 1] = q;
    }
  }

  // ---- last-block BN finalize (deterministic: counter reset by k_fir) ----
  __threadfence();
  __syncthreads();
  __shared__ int lastFlag;
  if (tid == 0) lastFlag = (atomicAdd(cnt, 1u) == (unsigned)(ABLK - 1)) ? 1 : 0;
  __syncthreads();
  if (lastFlag) {
    __threadfence();
    __shared__ float mv[8], ivv[8], bvv[8];
    if (tid < 16) {
      int cc = tid >> 1, qq = tid & 1;
      float s = 0.f;
#pragma unroll
      for (int k = 0; k < ABLK; ++k) s += part[k * 16 + cc * 2 + qq];
      float other = __shfl_xor(s, 1);
      if (qq == 0) {
        float mean = s * (1.0f / 256.0f);
        float var  = other * (1.0f / 256.0f) - mean * mean;
        mv[cc]  = mean;
        ivv[cc] = gamma[cc] * rsqrtf(var + 1e-5f);
        bvv[cc] = beta[cc];
      }
    }
    __syncthreads();
    for (int i = tid; i < BB * CC * 2; i += 256) {
      int cc = (i >> 1) & 7;
      out[i] = (oraw[i] - mv[cc]) * ivv[cc] + bvv[cc];
    }
  }
}

// ---------------------------------------------------------------------------
extern "C" void kernel_launch(void* const* d_in, const int* in_sizes, int n_in,
                              void* d_out, int out_size, void* d_ws, size_t ws_size,
                              hipStream_t stream) {
  const float* x   = (const float*)d_in[0];
  const float* wr  = (const float*)d_in[1];
  const float* wi  = (const float*)d_in[2];
  const float* wc  = (const float*)d_in[3];
  const float* wor = (const float*)d_in[4];
  const float* woi = (const float*)d_in[5];
  const float* gm  = (const float*)d_in[6];
  const float* bt  = (const float*)d_in[7];
  float* out = (float*)d_out;

  float* ws    = (float*)d_ws;
  float* fpart = ws;                                    // B*NTILES*160 = 655360 f32
  float* oraw  = fpart + (size_t)BB * NTILES * 160;     // 2048 f32
  float* part  = oraw + BB * CC * 2;                    // ABLK*16 = 1024 f32
  unsigned int* cnt = (unsigned int*)(part + ABLK * 16);

  k_fir<<<dim3(BTILES * NTILES), dim3(256), 0, stream>>>(x, wr, wi, fpart, cnt);
  k_nonlin<<<dim3(ABLK), dim3(256), 0, stream>>>(fpart, wc, wor, woi, gm, bt,
                                                 oraw, part, cnt, out);
}